// Round 5
// baseline (5387.062 us; speedup 1.0000x reference)
//
#include <hip/hip_runtime.h>

#define D0 128
#define D1 64
#define D2 32
#define DL 3

__device__ __forceinline__ float sigf(float x) {
    // sigmoid(x) = 1/(1+2^(-x*log2(e))); v_exp_f32 + v_rcp_f32, ~1 ulp
    float e = __builtin_amdgcn_exp2f(-1.44269504088896340736f * x);
    return __builtin_amdgcn_rcpf(1.0f + e);
}

// Lane-pair activation: parity 0 holds pre-activation a, parity 1 holds tangent da.
__device__ __forceinline__ float act_pair(float a, int parity) {
    float pe  = __shfl_xor(a, 1, 64);      // partner's accumulator (in-wave, xor 1)
    float pre = parity ? pe : a;
    float sv  = sigf(pre);
    return parity ? sv * (1.0f - sv) * a   // dh = s'(a) * da
                  : sv;                    // h  = s(a)
}

// 4 threads/sample: parity (value/tangent) x neuron-half (wave-level, so weight
// addresses stay wave-uniform -> s_load). Max live state ~72 VGPR by construction:
// a1[32], h2[32], g1[32], g2[32]; cross-half sums exchanged via 17-stride LDS
// (2-way banked = free). No input staging: direct float4 loads, L1 merges the
// 2-wave row reuse. (256,2) grants ~88 VGPR (R4-measured) > 72 peak -> no spill.
__global__ __launch_bounds__(256, 2) void sindy_fused(
    const float* __restrict__ x,  const float* __restrict__ dx,
    const float* __restrict__ W1, const float* __restrict__ b1,
    const float* __restrict__ W2, const float* __restrict__ b2,
    const float* __restrict__ W3, const float* __restrict__ b3,
    const float* __restrict__ V1, const float* __restrict__ c1,
    const float* __restrict__ V2, const float* __restrict__ c2,
    const float* __restrict__ V3, const float* __restrict__ c3,
    const float* __restrict__ Ew, const float* __restrict__ Eb,
    float* __restrict__ out, int n)
{
    const int tid    = threadIdx.x;
    const int parity = tid & 1;            // 0: value path, 1: tangent path
    const int lane   = tid & 63;
    const int wv     = tid >> 6;           // wave 0..3
    const int hw     = wv >> 1;            // neuron half (wave-uniform!)
    const int sg     = wv & 1;             // sample subgroup
    const int p      = sg * 32 + (lane >> 1);   // local sample 0..63
    const int s0     = blockIdx.x * 64;
    const int samp   = s0 + p;
    const int ptnr   = tid ^ 128;          // other-half thread, same sample+parity

    // Exchange buffer: stride 17 dwords -> (17*tid+i)%32 is 2-way per access (free).
    __shared__ float cmb[256][17];

    // ---------------- encoder layer 1: 128 -> 64 (this wave's 32 rows) ----------
    float a1[32];
    #pragma unroll
    for (int j = 0; j < 32; ++j) a1[j] = parity ? 0.0f : b1[hw * 32 + j];

    const float4* row4 = (const float4*)((parity ? dx : x) + (size_t)samp * D0);
    const float*  w1r  = W1 + (size_t)(hw * 32) * D0;
    #pragma unroll 1
    for (int kk = 0; kk < 8; ++kk) {       // 16 k per iter; NOT unrolled (pressure)
        float4 xv[4];
        #pragma unroll
        for (int f = 0; f < 4; ++f) xv[f] = row4[kk * 4 + f];
        #pragma unroll
        for (int j = 0; j < 32; ++j) {
            const float* wr = w1r + j * D0 + kk * 16;   // wave-uniform -> s_load
            #pragma unroll
            for (int f = 0; f < 4; ++f) {
                a1[j] = fmaf(wr[f * 4 + 0], xv[f].x, a1[j]);
                a1[j] = fmaf(wr[f * 4 + 1], xv[f].y, a1[j]);
                a1[j] = fmaf(wr[f * 4 + 2], xv[f].z, a1[j]);
                a1[j] = fmaf(wr[f * 4 + 3], xv[f].w, a1[j]);
            }
        }
    }
    #pragma unroll
    for (int j = 0; j < 32; ++j) a1[j] = act_pair(a1[j], parity);

    // ---------------- encoder layer 2: 64 -> 32 (partial over own k-half) -------
    float h2[32];
    #pragma unroll 1
    for (int r = 0; r < 2; ++r) {          // 16 outputs per round, 17-wide buffer
        float ap[16];
        #pragma unroll
        for (int j2 = 0; j2 < 16; ++j2) {
            int j = r * 16 + j2;
            float a = (hw == 0 && !parity) ? b2[j] : 0.0f;   // bias counted once
            #pragma unroll
            for (int k = 0; k < 32; ++k)
                a = fmaf(W2[j * D1 + hw * 32 + k], a1[k], a);
            ap[j2] = a;
        }
        __syncthreads();                   // prev round's reads done
        #pragma unroll
        for (int i = 0; i < 16; ++i) cmb[tid][i] = ap[i];
        __syncthreads();
        #pragma unroll
        for (int i = 0; i < 16; ++i) ap[i] += cmb[ptnr][i];
        #pragma unroll
        for (int i = 0; i < 16; ++i) h2[r * 16 + i] = act_pair(ap[i], parity);
    }

    // ---------------- encoder layer 3: 32 -> 3 (linear; both halves redundant) --
    float zz[DL];
    #pragma unroll
    for (int j = 0; j < DL; ++j) {
        float a = parity ? 0.0f : b3[j];
        #pragma unroll
        for (int k = 0; k < D2; ++k) a = fmaf(W3[j * D2 + k], h2[k], a);
        zz[j] = a;                          // even: z, odd: dz
    }

    // ---------------- write z / dz (half 0 only) --------------------------------
    const size_t n3   = (size_t)n * 3;
    const size_t srow = (size_t)samp * 3;
    if (hw == 0) {                          // wave-uniform branch
        float* zb = out + (parity ? n3 : 0);
        #pragma unroll
        for (int j = 0; j < DL; ++j) zb[srow + j] = zz[j];
    }

    // ---------------- SINDy library (22 terms) + dzb ----------------------------
    float th[22];
    th[0] = 1.0f; th[1] = 1.0f; th[2] = 1.0f;
    th[3] = zz[0]; th[4] = zz[1]; th[5] = zz[2];
    {
        int t = 6;
        #pragma unroll
        for (int i = 0; i < 3; ++i)
            #pragma unroll
            for (int j = i; j < 3; ++j) th[t++] = zz[i] * zz[j];
        #pragma unroll
        for (int i = 0; i < 3; ++i)
            #pragma unroll
            for (int j = i; j < 3; ++j)
                #pragma unroll
                for (int k = j; k < 3; ++k) th[t++] = zz[i] * zz[j] * zz[k];
    }
    float dzb[DL];
    #pragma unroll
    for (int j = 0; j < DL; ++j) {
        float a = Eb[j];
        #pragma unroll
        for (int q = 0; q < 22; ++q) a = fmaf(Ew[j * 22 + q], th[q], a);
        dzb[j] = a;
    }
    float qv[DL];
    #pragma unroll
    for (int k = 0; k < DL; ++k) {
        float t = __shfl_xor(dzb[k], 1, 64);
        qv[k] = parity ? t : zz[k];
    }
    if (hw == 0 && !parity) {
        #pragma unroll
        for (int j = 0; j < DL; ++j) out[2 * n3 + srow + j] = dzb[j];
    }

    // ---------------- decoder layer 1: 3 -> 32 (full per lane) ------------------
    float g1[32];
    #pragma unroll
    for (int j = 0; j < D2; ++j) {
        float a = parity ? 0.0f : c1[j];
        #pragma unroll
        for (int k = 0; k < DL; ++k) a = fmaf(V1[j * DL + k], qv[k], a);
        g1[j] = act_pair(a, parity);
    }

    // ---------------- decoder layer 2: 32 -> 64 (own output half) ---------------
    float g2[32];
    #pragma unroll
    for (int jj = 0; jj < 32; ++jj) {
        int j = hw * 32 + jj;               // wave-uniform row
        float a = parity ? 0.0f : c2[j];
        #pragma unroll
        for (int k = 0; k < D2; ++k) a = fmaf(V2[j * D2 + k], g1[k], a);
        g2[jj] = act_pair(a, parity);
    }

    // ---------------- decoder layer 3: 64 -> 128 (partial + exchange) -----------
    float* oxb  = out + (size_t)n * 9;
    float* odxb = out + (size_t)n * 137;
    #pragma unroll 1
    for (int c = 0; c < 8; ++c) {           // 16 outputs per chunk
        float pp[16];
        #pragma unroll
        for (int jj = 0; jj < 16; ++jj) {
            int j = c * 16 + jj;
            float a = (hw == 0 && !parity) ? c3[j] : 0.0f;
            #pragma unroll
            for (int k = 0; k < 32; ++k)
                a = fmaf(V3[j * D1 + hw * 32 + k], g2[k], a);
            pp[jj] = a;
        }
        __syncthreads();                    // prev chunk's reads done
        #pragma unroll
        for (int i = 0; i < 16; ++i) cmb[tid][i] = pp[i];
        __syncthreads();
        #pragma unroll
        for (int i = 0; i < 16; ++i) pp[i] += cmb[ptnr][i];
        if (hw == (c & 1)) {                // split store duty across halves
            float* dst = (parity ? odxb : oxb) + (size_t)samp * D0 + c * 16;
            #pragma unroll
            for (int i = 0; i < 16; i += 4) {
                float4 v;
                v.x = pp[i]; v.y = pp[i + 1]; v.z = pp[i + 2]; v.w = pp[i + 3];
                *(float4*)(dst + i) = v;
            }
        }
    }
}

extern "C" void kernel_launch(void* const* d_in, const int* in_sizes, int n_in,
                              void* d_out, int out_size, void* d_ws, size_t ws_size,
                              hipStream_t stream) {
    const float* x  = (const float*)d_in[0];
    const float* dx = (const float*)d_in[1];
    const float* W1 = (const float*)d_in[2];
    const float* b1 = (const float*)d_in[3];
    const float* W2 = (const float*)d_in[4];
    const float* b2 = (const float*)d_in[5];
    const float* W3 = (const float*)d_in[6];
    const float* b3 = (const float*)d_in[7];
    const float* V1 = (const float*)d_in[8];
    const float* c1 = (const float*)d_in[9];
    const float* V2 = (const float*)d_in[10];
    const float* c2 = (const float*)d_in[11];
    const float* V3 = (const float*)d_in[12];
    const float* c3 = (const float*)d_in[13];
    const float* Ew = (const float*)d_in[14];
    const float* Eb = (const float*)d_in[15];

    const int n = in_sizes[0] / D0;      // 262144
    const int grid = n / 64;             // 4096 blocks, 4 threads per sample

    sindy_fused<<<grid, 256, 0, stream>>>(x, dx, W1, b1, W2, b2, W3, b3,
                                          V1, c1, V2, c2, V3, c3, Ew, Eb,
                                          (float*)d_out, n);
}